// Round 14
// baseline (3250.869 us; speedup 1.0000x reference)
//
#include <hip/hip_runtime.h>

#define B_ 64
#define T_ 2048
#define F_ 8
#define H_ 128
#define RING_LD 68         // padded h1-ring row (dwords)
#define CHUNK 64
#define NCH (T_ / CHUNK)   // 32 chunks
#define GRING 16           // global h0 ring depth (chunks) per batch
#define H0_DW (CHUNK * 64) // dwords per published chunk (dense [64][64])
#define Z_LD 516           // padded zih1 row (f32), 16-tick window

typedef _Float16 v2h   __attribute__((ext_vector_type(2)));
typedef _Float16 f16x8 __attribute__((ext_vector_type(8)));
typedef float    f32x4 __attribute__((ext_vector_type(4)));

__device__ __forceinline__ unsigned pk2h(float lo, float hi) {
    v2h p;
    p[0] = (_Float16)lo;
    p[1] = (_Float16)hi;
    return __builtin_bit_cast(unsigned, p);
}

#if __has_builtin(__builtin_amdgcn_fdot2)
__device__ __forceinline__ float fdot2a(unsigned a, unsigned b, float c) {
    return __builtin_amdgcn_fdot2(__builtin_bit_cast(v2h, a),
                                  __builtin_bit_cast(v2h, b), c, false);
}
#else
__device__ __forceinline__ float fdot2a(unsigned a, unsigned b, float c) {
    v2h av = __builtin_bit_cast(v2h, a);
    v2h bv = __builtin_bit_cast(v2h, b);
    c += (float)av[0] * (float)bv[0];
    c += (float)av[1] * (float)bv[1];
    return c;
}
#endif

__device__ __forceinline__ float sigm(float x) {
    return 1.0f / (1.0f + __expf(-x));
}
__device__ __forceinline__ float tanh_f(float x) {
    float e = __expf(2.0f * x);
    return 1.0f - 2.0f / (e + 1.0f);
}

__device__ __forceinline__ f32x4 mfma16(f16x8 a, f16x8 b, f32x4 c) {
    return __builtin_amdgcn_mfma_f32_16x16x32_f16(a, b, c, 0, 0, 0);
}

#if __has_builtin(__builtin_amdgcn_mov_dpp)
template <int CTRL>
__device__ __forceinline__ float qperm(float v) {
    int i = __builtin_bit_cast(int, v);
    i = __builtin_amdgcn_mov_dpp(i, CTRL, 0xF, 0xF, true);
    return __builtin_bit_cast(float, i);
}
__device__ __forceinline__ float lane_xor1(float v) { return qperm<0xB1>(v); }
__device__ __forceinline__ float lane_xor2(float v) { return qperm<0x4E>(v); }
#else
__device__ __forceinline__ float lane_xor1(float v) {
    int i = __builtin_amdgcn_ds_swizzle(__builtin_bit_cast(int, v), 0x041F);
    return __builtin_bit_cast(float, i);
}
__device__ __forceinline__ float lane_xor2(float v) {
    int i = __builtin_amdgcn_ds_swizzle(__builtin_bit_cast(int, v), 0x081F);
    return __builtin_bit_cast(float, i);
}
#endif

// ---------------------------------------------------------------------------
// r14 = r13 pipeline with TWO independent batches interleaved per block
// (dual-chain latency hiding; weights shared: producer 68 dw VGPR, consumer
// 128 dw AGPR serve both batches). 32 producer + 32 consumer blocks.
// Consumer reads GEMM A-frags directly from the acquired global chunk
// (L2-resident) -> no h0c staging; zih1 is a 16-tick window per batch,
// recomputed per quarter. All per-tick math verbatim r13 (verified),
// duplicated with _0/_1 suffixes.
// ---------------------------------------------------------------------------
__global__ __launch_bounds__(512, 2)
void lstm2_pc4_kernel(const float* __restrict__ x,
                      const float* __restrict__ wih0,
                      const float* __restrict__ whh0,
                      const float* __restrict__ bih0,
                      const float* __restrict__ bhh0,
                      const float* __restrict__ wih1,
                      const float* __restrict__ whh1,
                      const float* __restrict__ bih1,
                      const float* __restrict__ bhh1,
                      const float* __restrict__ wlin,
                      const float* __restrict__ blin,
                      unsigned* __restrict__ h0g,
                      int* __restrict__ flags,
                      float* __restrict__ out)
{
    // consumer: ring0[64][68] | ring1[64][68] | z0[16][516]f32 | z1[16][516] | wlin[8][68]
    // producer: x0[8192] | x1[8192] | r0[64][64] | r1[64][64]
    __shared__ __align__(16) unsigned arena[25760];   // ~100.6 KB
    __shared__ float blin_f[F_];

    const int tid = threadIdx.x;
    int* prog = flags;        // producer -> consumer: chunks published
    int* done = flags + 64;   // consumer -> producer: chunks consumed

    if (blockIdx.x < 32) {
        // =================== PRODUCER: layer 0, batches b0,b1 ===================
        const int b0 = blockIdx.x * 2;
        const int b1 = b0 + 1;
        unsigned* x0 = arena;              // 8192 dwords
        unsigned* x1 = arena + 8192;
        unsigned* r0 = arena + 16384;      // [64][64]
        unsigned* r1 = arena + 20480;

        const int h_idx = tid >> 2;
        const int sub   = tid & 3;
        const int growA = (0x3120 >> (sub * 4)) & 0xF;   // {0,2,1,3}[sub]
        const int rowA  = growA * H_ + h_idx;

        {
            const float4* xp0 = (const float4*)(x + (size_t)b0 * T_ * F_);
            const float4* xp1 = (const float4*)(x + (size_t)b1 * T_ * F_);
            #pragma unroll
            for (int i = 0; i < 8; ++i) {
                int idx = tid + i * 512;
                float4 v0 = xp0[idx];
                float4 v1 = xp1[idx];
                x0[idx * 2 + 0] = pk2h(v0.x, v0.y);
                x0[idx * 2 + 1] = pk2h(v0.z, v0.w);
                x1[idx * 2 + 0] = pk2h(v1.x, v1.y);
                x1[idx * 2 + 1] = pk2h(v1.z, v1.w);
            }
        }

        unsigned rwih0[4];
        {
            const float4* p = (const float4*)(wih0 + (size_t)rowA * F_);
            float4 v0 = p[0], v1 = p[1];
            rwih0[0] = pk2h(v0.x, v0.y); rwih0[1] = pk2h(v0.z, v0.w);
            rwih0[2] = pk2h(v1.x, v1.y); rwih0[3] = pk2h(v1.z, v1.w);
        }
        unsigned rwhh0[64];
        {
            const float4* p = (const float4*)(whh0 + (size_t)rowA * H_);
            #pragma unroll
            for (int i = 0; i < 32; ++i) {
                float4 v = p[i];
                rwhh0[i * 2 + 0] = pk2h(v.x, v.y);
                rwhh0[i * 2 + 1] = pk2h(v.z, v.w);
            }
        }
        const float bias0 = bih0[rowA] + bhh0[rowA];

        if (tid < 64) { r0[63 * 64 + tid] = 0u; r1[63 * 64 + tid] = 0u; }
        __syncthreads();

        const bool is_g = (sub == 1);
        const bool lo2  = (sub < 2);
        float c0_0 = 0.0f, c0_1 = 0.0f;

        for (int t = 0; t < T_; ++t) {
            {
                // batch 0 + batch 1 interleaved (r13-verified 4-chain math x2)
                float aa0 = bias0, ab0 = 0.0f, ba0 = 0.0f, bb0 = 0.0f;
                float aa1 = bias0, ab1 = 0.0f, ba1 = 0.0f, bb1 = 0.0f;
                uint4 xv0 = *(const uint4*)&x0[t * 4];
                uint4 xv1 = *(const uint4*)&x1[t * 4];
                aa0 = fdot2a(rwih0[0], xv0.x, aa0);
                ab0 = fdot2a(rwih0[1], xv0.y, ab0);
                ba0 = fdot2a(rwih0[2], xv0.z, ba0);
                bb0 = fdot2a(rwih0[3], xv0.w, bb0);
                aa1 = fdot2a(rwih0[0], xv1.x, aa1);
                ab1 = fdot2a(rwih0[1], xv1.y, ab1);
                ba1 = fdot2a(rwih0[2], xv1.z, ba1);
                bb1 = fdot2a(rwih0[3], xv1.w, bb1);
                const unsigned* h0r = &r0[((t + 63) & 63) * 64];
                const unsigned* h1r = &r1[((t + 63) & 63) * 64];
                #pragma unroll
                for (int j = 0; j < 16; ++j) {
                    uint4 hv0 = *(const uint4*)&h0r[j * 4];
                    uint4 hv1 = *(const uint4*)&h1r[j * 4];
                    aa0 = fdot2a(rwhh0[j * 4 + 0], hv0.x, aa0);
                    ab0 = fdot2a(rwhh0[j * 4 + 1], hv0.y, ab0);
                    ba0 = fdot2a(rwhh0[j * 4 + 2], hv0.z, ba0);
                    bb0 = fdot2a(rwhh0[j * 4 + 3], hv0.w, bb0);
                    aa1 = fdot2a(rwhh0[j * 4 + 0], hv1.x, aa1);
                    ab1 = fdot2a(rwhh0[j * 4 + 1], hv1.y, ab1);
                    ba1 = fdot2a(rwhh0[j * 4 + 2], hv1.z, ba1);
                    bb1 = fdot2a(rwhh0[j * 4 + 3], hv1.w, bb1);
                }
                float a0 = (aa0 + ab0) + (ba0 + bb0);
                float a1 = (aa1 + ab1) + (ba1 + bb1);
                float xin0 = is_g ? 2.0f * a0 : a0;
                float xin1 = is_g ? 2.0f * a1 : a1;
                float s0 = sigm(xin0);
                float s1v = sigm(xin1);
                float act0 = is_g ? 2.0f * s0 - 1.0f : s0;
                float act1 = is_g ? 2.0f * s1v - 1.0f : s1v;
                float sx0 = lane_xor1(act0);
                float sx1 = lane_xor1(act1);
                float p0 = lo2 ? act0 * sx0 : (sub == 2 ? act0 : sx0) * c0_0;
                float p1 = lo2 ? act1 * sx1 : (sub == 2 ? act1 : sx1) * c0_1;
                float cn0 = p0 + lane_xor2(p0);
                float cn1 = p1 + lane_xor2(p1);
                c0_0 = cn0;
                c0_1 = cn1;
                float ov0 = (sub == 2) ? sx0 : act0;
                float ov1 = (sub == 2) ? sx1 : act1;
                float hh0 = ov0 * tanh_f(cn0);
                float hh1 = ov1 * tanh_f(cn1);
                if (sub == 2) {
                    ((_Float16*)&r0[(t & 63) * 64])[h_idx] = (_Float16)hh0;
                    ((_Float16*)&r1[(t & 63) * 64])[h_idx] = (_Float16)hh1;
                }
            }
            __syncthreads();

            if ((t & 63) == 63) {
                const int c = t >> 6;
                if (c >= GRING) {
                    while (__hip_atomic_load(&done[b0], __ATOMIC_ACQUIRE,
                                             __HIP_MEMORY_SCOPE_AGENT) < c - GRING + 1 ||
                           __hip_atomic_load(&done[b1], __ATOMIC_ACQUIRE,
                                             __HIP_MEMORY_SCOPE_AGENT) < c - GRING + 1)
                        __builtin_amdgcn_s_sleep(8);
                    __syncthreads();
                }
                unsigned* d0 = h0g + ((size_t)b0 * GRING + (c & (GRING - 1))) * H0_DW;
                unsigned* d1 = h0g + ((size_t)b1 * GRING + (c & (GRING - 1))) * H0_DW;
                uint4 u0 = *(const uint4*)&r0[tid * 8];
                uint4 u1 = *(const uint4*)&r0[tid * 8 + 4];
                uint4 u2 = *(const uint4*)&r1[tid * 8];
                uint4 u3 = *(const uint4*)&r1[tid * 8 + 4];
                *(uint4*)&d0[tid * 8]     = u0;
                *(uint4*)&d0[tid * 8 + 4] = u1;
                *(uint4*)&d1[tid * 8]     = u2;
                *(uint4*)&d1[tid * 8 + 4] = u3;
                __syncthreads();   // stores drained before release
                if (tid == 0) {
                    __hip_atomic_store(&prog[b0], c + 1, __ATOMIC_RELEASE,
                                       __HIP_MEMORY_SCOPE_AGENT);
                    __hip_atomic_store(&prog[b1], c + 1, __ATOMIC_RELEASE,
                                       __HIP_MEMORY_SCOPE_AGENT);
                }
            }
        }
    } else {
        // =================== CONSUMER: layer 1 + OUT, batches b0,b1 ===================
        const int cb = blockIdx.x - 32;
        const int b0 = cb * 2;
        const int b1 = b0 + 1;
        unsigned* ring0  = arena;                      // [64][68]
        unsigned* ring1  = arena + 4352;
        float*    z0     = (float*)(arena + 8704);     // [16][516]
        float*    z1     = (float*)(arena + 16960);
        unsigned* wlin_p = arena + 25216;              // [8][68]

        const int w   = tid >> 6;
        const int l   = tid & 63;
        const int n   = l & 15;
        const int grp = l >> 4;

        f16x8 wih1f[4][4], whh1f[4][4];
        #pragma unroll
        for (int j = 0; j < 4; ++j) {
            const int row = j * H_ + w * 16 + n;
            #pragma unroll
            for (int s = 0; s < 4; ++s) {
                const float* p1 = wih1 + (size_t)row * H_ + s * 32 + grp * 8;
                const float* p2 = whh1 + (size_t)row * H_ + s * 32 + grp * 8;
                f16x8 f1, f2;
                #pragma unroll
                for (int jj = 0; jj < 8; ++jj) {
                    f1[jj] = (_Float16)p1[jj];
                    f2[jj] = (_Float16)p2[jj];
                }
                wih1f[j][s] = f1;
                whh1f[j][s] = f2;
            }
        }
        #pragma unroll
        for (int j = 0; j < 4; ++j)
            #pragma unroll
            for (int s = 0; s < 4; ++s) {
                asm("" : "+a"(wih1f[j][s]));
                asm("" : "+a"(whh1f[j][s]));
            }

        float bb1[4];
        #pragma unroll
        for (int j = 0; j < 4; ++j) {
            const int row = j * H_ + w * 16 + n;
            bb1[j] = bih1[row] + bhh1[row];
        }
        {
            float2 v = ((const float2*)wlin)[tid];
            wlin_p[(tid >> 6) * RING_LD + (tid & 63)] = pk2h(v.x, v.y);
        }
        if (tid < F_) blin_f[tid] = blin[tid];
        if (tid < 64) {
            ring0[63 * RING_LD + tid] = 0u;
            ring1[63 * RING_LD + tid] = 0u;
        }
        __syncthreads();

        float c1_0 = 0.0f, c1_1 = 0.0f;
        const f32x4 Z4 = {0.0f, 0.0f, 0.0f, 0.0f};

        for (int c = 0; c < NCH; ++c) {
            while (__hip_atomic_load(&prog[b0], __ATOMIC_ACQUIRE,
                                     __HIP_MEMORY_SCOPE_AGENT) < c + 1 ||
                   __hip_atomic_load(&prog[b1], __ATOMIC_ACQUIRE,
                                     __HIP_MEMORY_SCOPE_AGENT) < c + 1)
                __builtin_amdgcn_s_sleep(8);
            const unsigned* src0 = h0g + ((size_t)b0 * GRING + (c & (GRING - 1))) * H0_DW;
            const unsigned* src1 = h0g + ((size_t)b1 * GRING + (c & (GRING - 1))) * H0_DW;

            for (int tk = 0; tk < CHUNK; ++tk) {
                // ---- quarter boundary: zih1 GEMM for ticks [q*16, q*16+16) ----
                if ((tk & 15) == 0) {
                    const int q = tk >> 4;
                    const unsigned* a0p = src0 + (q * 16 + n) * 64;
                    const unsigned* a1p = src1 + (q * 16 + n) * 64;
                    f32x4 d0 = Z4, d1 = Z4, d2 = Z4, d3 = Z4;
                    f32x4 e0 = Z4, e1 = Z4, e2 = Z4, e3 = Z4;
                    #pragma unroll
                    for (int s = 0; s < 4; ++s) {
                        f16x8 ah0 = __builtin_bit_cast(
                            f16x8, *(const uint4*)&a0p[s * 16 + grp * 4]);
                        f16x8 ah1 = __builtin_bit_cast(
                            f16x8, *(const uint4*)&a1p[s * 16 + grp * 4]);
                        d0 = mfma16(ah0, wih1f[0][s], d0);
                        d1 = mfma16(ah0, wih1f[1][s], d1);
                        d2 = mfma16(ah0, wih1f[2][s], d2);
                        d3 = mfma16(ah0, wih1f[3][s], d3);
                        e0 = mfma16(ah1, wih1f[0][s], e0);
                        e1 = mfma16(ah1, wih1f[1][s], e1);
                        e2 = mfma16(ah1, wih1f[2][s], e2);
                        e3 = mfma16(ah1, wih1f[3][s], e3);
                    }
                    #pragma unroll
                    for (int reg = 0; reg < 4; ++reg) {
                        const int zr = (grp * 4 + reg) * Z_LD + w * 16 + n;
                        z0[zr + 0 * H_] = d0[reg];
                        z0[zr + 1 * H_] = d1[reg];
                        z0[zr + 2 * H_] = d2[reg];
                        z0[zr + 3 * H_] = d3[reg];
                        z1[zr + 0 * H_] = e0[reg];
                        z1[zr + 1 * H_] = e1[reg];
                        z1[zr + 2 * H_] = e2[reg];
                        z1[zr + 3 * H_] = e3[reg];
                    }
                    // no barrier: wave w writes/reads only its own gate-cols
                }

                // ---- serial tick (r13-verified math x2, interleaved) ----
                const int t = c * CHUNK + tk;
                const unsigned* h1r0 = &ring0[((t + 63) & 63) * RING_LD];
                const unsigned* h1r1 = &ring1[((t + 63) & 63) * RING_LD];
                f32x4 a0, a1, a2, a3, g0, g1, g2, g3;
                {
                    f16x8 ah0 = __builtin_bit_cast(f16x8, *(const uint4*)&h1r0[grp * 4]);
                    f16x8 ah1 = __builtin_bit_cast(f16x8, *(const uint4*)&h1r1[grp * 4]);
                    a0 = mfma16(ah0, whh1f[0][0], Z4);
                    a1 = mfma16(ah0, whh1f[1][0], Z4);
                    a2 = mfma16(ah0, whh1f[2][0], Z4);
                    a3 = mfma16(ah0, whh1f[3][0], Z4);
                    g0 = mfma16(ah1, whh1f[0][0], Z4);
                    g1 = mfma16(ah1, whh1f[1][0], Z4);
                    g2 = mfma16(ah1, whh1f[2][0], Z4);
                    g3 = mfma16(ah1, whh1f[3][0], Z4);
                }
                #pragma unroll
                for (int s = 1; s < 4; ++s) {
                    f16x8 ah0 = __builtin_bit_cast(
                        f16x8, *(const uint4*)&h1r0[s * 16 + grp * 4]);
                    f16x8 ah1 = __builtin_bit_cast(
                        f16x8, *(const uint4*)&h1r1[s * 16 + grp * 4]);
                    a0 = mfma16(ah0, whh1f[0][s], a0);
                    a1 = mfma16(ah0, whh1f[1][s], a1);
                    a2 = mfma16(ah0, whh1f[2][s], a2);
                    a3 = mfma16(ah0, whh1f[3][s], a3);
                    g0 = mfma16(ah1, whh1f[0][s], g0);
                    g1 = mfma16(ah1, whh1f[1][s], g1);
                    g2 = mfma16(ah1, whh1f[2][s], g2);
                    g3 = mfma16(ah1, whh1f[3][s], g3);
                }
                const float* zp0 = &z0[(tk & 15) * Z_LD + w * 16 + n];
                const float* zp1 = &z1[(tk & 15) * Z_LD + w * 16 + n];
                float gi0 = sigm(a0[0] + zp0[0 * H_] + bb1[0]);
                float gf0 = sigm(a1[0] + zp0[1 * H_] + bb1[1]);
                float gg0 = tanh_f(a2[0] + zp0[2 * H_] + bb1[2]);
                float go0 = sigm(a3[0] + zp0[3 * H_] + bb1[3]);
                float gi1 = sigm(g0[0] + zp1[0 * H_] + bb1[0]);
                float gf1 = sigm(g1[0] + zp1[1 * H_] + bb1[1]);
                float gg1 = tanh_f(g2[0] + zp1[2 * H_] + bb1[2]);
                float go1 = sigm(g3[0] + zp1[3 * H_] + bb1[3]);
                c1_0 = gf0 * c1_0 + gi0 * gg0;
                c1_1 = gf1 * c1_1 + gi1 * gg1;
                float hh0 = go0 * tanh_f(c1_0);
                float hh1 = go1 * tanh_f(c1_1);
                if (l < 16) {
                    ((_Float16*)&ring0[(t & 63) * RING_LD])[w * 16 + l] = (_Float16)hh0;
                    ((_Float16*)&ring1[(t & 63) * RING_LD])[w * 16 + l] = (_Float16)hh1;
                }
                __syncthreads();   // h1(t) visible (both batches)
            }

            // ---- OUT burst for this chunk: 1024 outputs, 2 per thread ----
            {
                const int half = tid >> 8;              // 0: batch0, 1: batch1
                const unsigned* ringX = half ? ring1 : ring0;
                const int bX = half ? b1 : b0;
                #pragma unroll
                for (int r = 0; r < 2; ++r) {
                    const int idx    = (tid & 255) + r * 256;   // 0..511
                    const int tick_i = idx >> 3;
                    const int fo     = idx & 7;
                    const unsigned* hp = &ringX[tick_i * RING_LD];
                    const unsigned* wv = &wlin_p[fo * RING_LD];
                    float a = 0.0f;
                    #pragma unroll
                    for (int j = 0; j < 16; ++j) {
                        uint4 hv = *(const uint4*)&hp[j * 4];
                        uint4 wq = *(const uint4*)&wv[j * 4];
                        a = fdot2a(wq.x, hv.x, a);
                        a = fdot2a(wq.y, hv.y, a);
                        a = fdot2a(wq.z, hv.z, a);
                        a = fdot2a(wq.w, hv.w, a);
                    }
                    out[(size_t)bX * T_ * F_ + (size_t)c * CHUNK * F_ + idx] =
                        a + blin_f[fo];
                }
            }
            __syncthreads();   // out reads of ring done before next chunk overwrites
            if (tid == 0) {
                __hip_atomic_store(&done[b0], c + 1, __ATOMIC_RELAXED,
                                   __HIP_MEMORY_SCOPE_AGENT);
                __hip_atomic_store(&done[b1], c + 1, __ATOMIC_RELAXED,
                                   __HIP_MEMORY_SCOPE_AGENT);
            }
        }
    }
}

// ===================== Fallback (round-5 verified, 3162 us) =====================
__global__ __launch_bounds__(512, 2)
void lstm2_burst_kernel(const float* __restrict__ x,
                        const float* __restrict__ wih0,
                        const float* __restrict__ whh0,
                        const float* __restrict__ bih0,
                        const float* __restrict__ bhh0,
                        const float* __restrict__ wih1,
                        const float* __restrict__ whh1,
                        const float* __restrict__ bih1,
                        const float* __restrict__ bhh1,
                        const float* __restrict__ wlin,
                        const float* __restrict__ blin,
                        float* __restrict__ out)
{
    __shared__ __align__(16) unsigned x_lds[T_ * F_ / 2];
    __shared__ __align__(16) unsigned h0_p[2][H_ / 2];
    __shared__ __align__(16) unsigned h1_ring[64 * RING_LD];
    __shared__ __align__(16) unsigned wlin_p[F_ * RING_LD];
    __shared__ float blin_f[F_];

    const int tid   = threadIdx.x;
    const int b     = blockIdx.x;
    const int h_idx = tid >> 2;
    const int sub   = tid & 3;
    const int grow  = (0x3120 >> (sub * 4)) & 0xF;
    const int row   = grow * H_ + h_idx;

    const float4* xp = (const float4*)(x + (size_t)b * T_ * F_);
    #pragma unroll
    for (int i = 0; i < 8; ++i) {
        int idx = tid + i * 512;
        float4 v = xp[idx];
        x_lds[idx * 2 + 0] = pk2h(v.x, v.y);
        x_lds[idx * 2 + 1] = pk2h(v.z, v.w);
    }

    unsigned rwih0[4];
    {
        const float4* p = (const float4*)(wih0 + (size_t)row * F_);
        float4 v0 = p[0], v1 = p[1];
        rwih0[0] = pk2h(v0.x, v0.y); rwih0[1] = pk2h(v0.z, v0.w);
        rwih0[2] = pk2h(v1.x, v1.y); rwih0[3] = pk2h(v1.z, v1.w);
    }
    unsigned rwhh0[64], rwih1[64], rwhh1[64];
    {
        const float4* p = (const float4*)(whh0 + (size_t)row * H_);
        #pragma unroll
        for (int i = 0; i < 32; ++i) {
            float4 v = p[i];
            rwhh0[i * 2 + 0] = pk2h(v.x, v.y);
            rwhh0[i * 2 + 1] = pk2h(v.z, v.w);
        }
    }
    {
        const float4* p = (const float4*)(wih1 + (size_t)row * H_);
        #pragma unroll
        for (int i = 0; i < 32; ++i) {
            float4 v = p[i];
            rwih1[i * 2 + 0] = pk2h(v.x, v.y);
            rwih1[i * 2 + 1] = pk2h(v.z, v.w);
        }
    }
    {
        const float4* p = (const float4*)(whh1 + (size_t)row * H_);
        #pragma unroll
        for (int i = 0; i < 32; ++i) {
            float4 v = p[i];
            rwhh1[i * 2 + 0] = pk2h(v.x, v.y);
            rwhh1[i * 2 + 1] = pk2h(v.z, v.w);
        }
    }
    const float bias0 = bih0[row] + bhh0[row];
    const float bias1 = bih1[row] + bhh1[row];

    {
        int r = tid >> 6, c = tid & 63;
        float2 v = ((const float2*)wlin)[r * 64 + c];
        wlin_p[r * RING_LD + c] = pk2h(v.x, v.y);
    }
    if (tid < F_) blin_f[tid] = blin[tid];
    if (tid < H_ / 2) { h0_p[0][tid] = 0u; h0_p[1][tid] = 0u; }
    if (tid < H_ / 2) h1_ring[63 * RING_LD + tid] = 0u;
    __syncthreads();

    const bool is_g = (sub == 1);
    const bool lo2  = (sub < 2);
    float c0 = 0.0f, c1 = 0.0f;

    for (int t = 0; t < T_; ++t) {
        const int rp = (t + 1) & 1;
        const int wp = t & 1;
        {
            float aa = bias0, ab = 0.0f;
            uint4 xv = *(const uint4*)&x_lds[t * 4];
            aa = fdot2a(rwih0[0], xv.x, aa);
            ab = fdot2a(rwih0[1], xv.y, ab);
            aa = fdot2a(rwih0[2], xv.z, aa);
            ab = fdot2a(rwih0[3], xv.w, ab);
            const unsigned* hr = &h0_p[rp][0];
            #pragma unroll
            for (int j = 0; j < 16; ++j) {
                uint4 hv = *(const uint4*)&hr[j * 4];
                aa = fdot2a(rwhh0[j * 4 + 0], hv.x, aa);
                ab = fdot2a(rwhh0[j * 4 + 1], hv.y, ab);
                aa = fdot2a(rwhh0[j * 4 + 2], hv.z, aa);
                ab = fdot2a(rwhh0[j * 4 + 3], hv.w, ab);
            }
            float a = aa + ab;
            float xin = is_g ? 2.0f * a : a;
            float s   = sigm(xin);
            float act = is_g ? 2.0f * s - 1.0f : s;
            float s1  = lane_xor1(act);
            float p   = lo2 ? act * s1 : (sub == 2 ? act : s1) * c0;
            float cn  = p + lane_xor2(p);
            c0 = cn;
            float oval = (sub == 2) ? s1 : act;
            float h = oval * tanh_f(cn);
            if (sub == 2) ((_Float16*)&h0_p[wp][0])[h_idx] = (_Float16)h;
        }
        __syncthreads();
        {
            float aa = bias1, ab = 0.0f, ba = 0.0f, bb = 0.0f;
            const unsigned* h0r = &h0_p[wp][0];
            const unsigned* h1r = &h1_ring[((t + 63) & 63) * RING_LD];
            #pragma unroll
            for (int j = 0; j < 16; ++j) {
                uint4 hv0 = *(const uint4*)&h0r[j * 4];
                uint4 hv1 = *(const uint4*)&h1r[j * 4];
                aa = fdot2a(rwih1[j * 4 + 0], hv0.x, aa);
                ab = fdot2a(rwih1[j * 4 + 1], hv0.y, ab);
                aa = fdot2a(rwih1[j * 4 + 2], hv0.z, aa);
                ab = fdot2a(rwih1[j * 4 + 3], hv0.w, ab);
                ba = fdot2a(rwhh1[j * 4 + 0], hv1.x, ba);
                bb = fdot2a(rwhh1[j * 4 + 1], hv1.y, bb);
                ba = fdot2a(rwhh1[j * 4 + 2], hv1.z, ba);
                bb = fdot2a(rwhh1[j * 4 + 3], hv1.w, bb);
            }
            float a = (aa + ab) + (ba + bb);
            float xin = is_g ? 2.0f * a : a;
            float s   = sigm(xin);
            float act = is_g ? 2.0f * s - 1.0f : s;
            float s1  = lane_xor1(act);
            float p   = lo2 ? act * s1 : (sub == 2 ? act : s1) * c1;
            float cn  = p + lane_xor2(p);
            c1 = cn;
            float oval = (sub == 2) ? s1 : act;
            float h = oval * tanh_f(cn);
            if (sub == 2)
                ((_Float16*)&h1_ring[(t & 63) * RING_LD])[h_idx] = (_Float16)h;
        }
        __syncthreads();
        if ((t & 63) == 63) {
            const int tick_i = tid >> 3;
            const int fo     = tid & 7;
            const unsigned* hp = &h1_ring[tick_i * RING_LD];
            const unsigned* wv = &wlin_p[fo * RING_LD];
            float a = 0.0f;
            #pragma unroll
            for (int j = 0; j < 16; ++j) {
                uint4 hv = *(const uint4*)&hp[j * 4];
                uint4 wq = *(const uint4*)&wv[j * 4];
                a = fdot2a(wq.x, hv.x, a);
                a = fdot2a(wq.y, hv.y, a);
                a = fdot2a(wq.z, hv.z, a);
                a = fdot2a(wq.w, hv.w, a);
            }
            out[(size_t)b * T_ * F_ + (size_t)(t - 63) * F_ + tid] = a + blin_f[fo];
        }
    }
}

extern "C" void kernel_launch(void* const* d_in, const int* in_sizes, int n_in,
                              void* d_out, int out_size, void* d_ws, size_t ws_size,
                              hipStream_t stream) {
    const float* x    = (const float*)d_in[0];
    const float* wih0 = (const float*)d_in[1];
    const float* whh0 = (const float*)d_in[2];
    const float* bih0 = (const float*)d_in[3];
    const float* bhh0 = (const float*)d_in[4];
    const float* wih1 = (const float*)d_in[5];
    const float* whh1 = (const float*)d_in[6];
    const float* bih1 = (const float*)d_in[7];
    const float* bhh1 = (const float*)d_in[8];
    const float* wlin = (const float*)d_in[9];
    const float* blin = (const float*)d_in[10];
    float* out = (float*)d_out;

    const size_t h0_bytes = (size_t)B_ * GRING * H0_DW * sizeof(unsigned);  // 16 MB
    const size_t need = h0_bytes + 512;
    if (d_ws != nullptr && ws_size >= need) {
        unsigned* h0g = (unsigned*)d_ws;
        int* flags = (int*)((char*)d_ws + h0_bytes);   // prog[64], done[64]
        hipMemsetAsync(flags, 0, 512, stream);
        lstm2_pc4_kernel<<<dim3(64), dim3(512), 0, stream>>>(
            x, wih0, whh0, bih0, bhh0, wih1, whh1, bih1, bhh1, wlin, blin,
            h0g, flags, out);
    } else {
        lstm2_burst_kernel<<<dim3(B_), dim3(512), 0, stream>>>(
            x, wih0, whh0, bih0, bhh0, wih1, whh1, bih1, bhh1, wlin, blin, out);
    }
}

// Round 15
// 1478.615 us; speedup vs baseline: 2.1986x; 2.1986x over previous
//
#include <hip/hip_runtime.h>

#define B_ 64
#define T_ 2048
#define F_ 8
#define H_ 128
#define RING_LD 68         // padded h1-ring row (dwords)
#define CHUNK 64
#define NCH (T_ / CHUNK)   // 32 chunks
#define GRING 16           // global h0 ring depth (chunks) per batch
#define H0_DW (CHUNK * 64) // dwords per published chunk (dense [64][64])
#define Z_LD 516           // padded z row (f32)

typedef _Float16 v2h   __attribute__((ext_vector_type(2)));
typedef _Float16 f16x8 __attribute__((ext_vector_type(8)));
typedef float    f32x4 __attribute__((ext_vector_type(4)));

__device__ __forceinline__ unsigned pk2h(float lo, float hi) {
    v2h p;
    p[0] = (_Float16)lo;
    p[1] = (_Float16)hi;
    return __builtin_bit_cast(unsigned, p);
}

#if __has_builtin(__builtin_amdgcn_fdot2)
__device__ __forceinline__ float fdot2a(unsigned a, unsigned b, float c) {
    return __builtin_amdgcn_fdot2(__builtin_bit_cast(v2h, a),
                                  __builtin_bit_cast(v2h, b), c, false);
}
#else
__device__ __forceinline__ float fdot2a(unsigned a, unsigned b, float c) {
    v2h av = __builtin_bit_cast(v2h, a);
    v2h bv = __builtin_bit_cast(v2h, b);
    c += (float)av[0] * (float)bv[0];
    c += (float)av[1] * (float)bv[1];
    return c;
}
#endif

__device__ __forceinline__ float sigm(float x) {
    return 1.0f / (1.0f + __expf(-x));
}
__device__ __forceinline__ float tanh_f(float x) {
    float e = __expf(2.0f * x);
    return 1.0f - 2.0f / (e + 1.0f);
}

__device__ __forceinline__ f32x4 mfma16(f16x8 a, f16x8 b, f32x4 c) {
    return __builtin_amdgcn_mfma_f32_16x16x32_f16(a, b, c, 0, 0, 0);
}

#if __has_builtin(__builtin_amdgcn_mov_dpp)
template <int CTRL>
__device__ __forceinline__ float qperm(float v) {
    int i = __builtin_bit_cast(int, v);
    i = __builtin_amdgcn_mov_dpp(i, CTRL, 0xF, 0xF, true);
    return __builtin_bit_cast(float, i);
}
__device__ __forceinline__ float lane_xor1(float v) { return qperm<0xB1>(v); }
__device__ __forceinline__ float lane_xor2(float v) { return qperm<0x4E>(v); }
#else
__device__ __forceinline__ float lane_xor1(float v) {
    int i = __builtin_amdgcn_ds_swizzle(__builtin_bit_cast(int, v), 0x041F);
    return __builtin_bit_cast(float, i);
}
__device__ __forceinline__ float lane_xor2(float v) {
    int i = __builtin_amdgcn_ds_swizzle(__builtin_bit_cast(int, v), 0x081F);
    return __builtin_bit_cast(float, i);
}
#endif

// ---------------------------------------------------------------------------
// r15 = r13 pipeline (verified, 1494us) with the PRODUCER rebuilt to mirror
// the r13 consumer's verified tick shape:
//   - zih0 = Wih0 * x(t) precomputed per 16-tick quarter as a tiny MFMA GEMM
//     (K=8 zero-padded to 32; A/D mapping identical to the r13-verified zih1
//     GEMM; 4 MFMAs/wave/quarter).
//   - Whh0 held as 16 B-frags = exactly 128 dwords pinned "+a" (AGPR, read
//     natively by MFMA — r11/r13-proven).
//   - Serial tick: 4 broadcast ring reads + 4-deep MFMA chain + z/bias add +
//     PER-LANE activations (each lane owns all 4 gates of its h; the quad-DPP
//     exchange and {0,2,1,3} gate mapping are gone).
// Consumer, handoff protocol, OUT burst: byte-identical r13.
// r14 post-mortem: dual-batch interleave gave 0% overlap (2.15x tick for 2
// batches) -> stages are NOT cross-wave-latency-bound; attack stage max.
// ---------------------------------------------------------------------------
__global__ __launch_bounds__(512, 2)
void lstm2_pc5_kernel(const float* __restrict__ x,
                      const float* __restrict__ wih0,
                      const float* __restrict__ whh0,
                      const float* __restrict__ bih0,
                      const float* __restrict__ bhh0,
                      const float* __restrict__ wih1,
                      const float* __restrict__ whh1,
                      const float* __restrict__ bih1,
                      const float* __restrict__ bhh1,
                      const float* __restrict__ wlin,
                      const float* __restrict__ blin,
                      unsigned* __restrict__ h0g,
                      int* __restrict__ flags,
                      float* __restrict__ out)
{
    // consumer: h0c[64][68] | h1ring[64][68] | zih1[32][516]f32 | wlin[8][68]
    // producer: x_lds[8192] | ring[64][64] | z0[16][516]f32
    __shared__ __align__(16) unsigned arena[25760];   // ~100.6 KB
    __shared__ float blin_f[F_];

    const int tid = threadIdx.x;
    int* prog = flags;        // producer -> consumer: chunks published
    int* done = flags + 64;   // consumer -> producer: chunks consumed

    const int w   = tid >> 6;     // wave 0..7
    const int l   = tid & 63;     // lane
    const int n   = l & 15;       // fragment column / A-row index
    const int grp = l >> 4;       // k-slice group 0..3

    if (blockIdx.x < 64) {
        // =================== PRODUCER: layer 0 (MFMA tick, r15) ===================
        const int b = blockIdx.x;
        unsigned* x_lds = arena;                     // 8192 dwords
        unsigned* ring  = arena + 8192;              // [64][64] h0 ring
        float*    z0    = (float*)(arena + 12288);   // [16][516] f32

        const float4* xp = (const float4*)(x + (size_t)b * T_ * F_);
        #pragma unroll
        for (int i = 0; i < 8; ++i) {
            int idx = tid + i * 512;
            float4 v = xp[idx];
            x_lds[idx * 2 + 0] = pk2h(v.x, v.y);
            x_lds[idx * 2 + 1] = pk2h(v.z, v.w);
        }

        // Whh0 as B-frags, pinned AGPR (exactly 128 dwords)
        // frag [j][s]: elem jj = Whh0[j*128 + w*16 + n][s*32 + grp*8 + jj]
        f16x8 whh0f[4][4];
        #pragma unroll
        for (int j = 0; j < 4; ++j) {
            const int row = j * H_ + w * 16 + n;
            #pragma unroll
            for (int s = 0; s < 4; ++s) {
                const float* p0 = whh0 + (size_t)row * H_ + s * 32 + grp * 8;
                f16x8 f0;
                #pragma unroll
                for (int jj = 0; jj < 8; ++jj) f0[jj] = (_Float16)p0[jj];
                whh0f[j][s] = f0;
            }
        }
        #pragma unroll
        for (int j = 0; j < 4; ++j)
            #pragma unroll
            for (int s = 0; s < 4; ++s)
                asm("" : "+a"(whh0f[j][s]));

        // Wih0 B-frags (K=8 padded: only grp==0 lanes carry nonzero)
        f16x8 wih0f[4];
        #pragma unroll
        for (int j = 0; j < 4; ++j) {
            f16x8 f0 = {};
            if (grp == 0) {
                const float* p = wih0 + (size_t)(j * H_ + w * 16 + n) * F_;
                #pragma unroll
                for (int jj = 0; jj < 8; ++jj) f0[jj] = (_Float16)p[jj];
            }
            wih0f[j] = f0;
        }

        float bb0[4];
        #pragma unroll
        for (int j = 0; j < 4; ++j) {
            const int row = j * H_ + w * 16 + n;
            bb0[j] = bih0[row] + bhh0[row];
        }

        if (tid < 64) ring[63 * 64 + tid] = 0u;   // h0(-1) = 0
        __syncthreads();

        float c0 = 0.0f;
        const f32x4 Z4 = {0.0f, 0.0f, 0.0f, 0.0f};

        for (int ch = 0; ch < NCH; ++ch) {
            for (int q = 0; q < 4; ++q) {
                // ---- zih0 GEMM for ticks [ch*64+q*16, +16) (4 MFMAs) ----
                {
                    const int tg = ch * CHUNK + q * 16 + n;   // A row n = tick
                    f16x8 ax = (f16x8){};
                    if (grp == 0)
                        ax = __builtin_bit_cast(f16x8, *(const uint4*)&x_lds[tg * 4]);
                    f32x4 d0 = mfma16(ax, wih0f[0], Z4);
                    f32x4 d1 = mfma16(ax, wih0f[1], Z4);
                    f32x4 d2 = mfma16(ax, wih0f[2], Z4);
                    f32x4 d3 = mfma16(ax, wih0f[3], Z4);
                    #pragma unroll
                    for (int reg = 0; reg < 4; ++reg) {
                        const int zr = (grp * 4 + reg) * Z_LD + w * 16 + n;
                        z0[zr + 0 * H_] = d0[reg];
                        z0[zr + 1 * H_] = d1[reg];
                        z0[zr + 2 * H_] = d2[reg];
                        z0[zr + 3 * H_] = d3[reg];
                    }
                    // no barrier: wave w writes/reads only its own gate-cols
                }

                // ---- 16 serial ticks (consumer-shaped: 4-deep MFMA chain) ----
                for (int tk = 0; tk < 16; ++tk) {
                    const int t = ch * CHUNK + q * 16 + tk;
                    const unsigned* hr = &ring[((t + 63) & 63) * 64];   // h0(t-1)
                    f32x4 a0, a1, a2, a3;
                    {
                        f16x8 ah = __builtin_bit_cast(f16x8, *(const uint4*)&hr[grp * 4]);
                        a0 = mfma16(ah, whh0f[0][0], Z4);
                        a1 = mfma16(ah, whh0f[1][0], Z4);
                        a2 = mfma16(ah, whh0f[2][0], Z4);
                        a3 = mfma16(ah, whh0f[3][0], Z4);
                    }
                    #pragma unroll
                    for (int s = 1; s < 4; ++s) {
                        f16x8 ah = __builtin_bit_cast(
                            f16x8, *(const uint4*)&hr[s * 16 + grp * 4]);
                        a0 = mfma16(ah, whh0f[0][s], a0);
                        a1 = mfma16(ah, whh0f[1][s], a1);
                        a2 = mfma16(ah, whh0f[2][s], a2);
                        a3 = mfma16(ah, whh0f[3][s], a3);
                    }
                    const float* zz = &z0[tk * Z_LD + w * 16 + n];
                    float gi = sigm(a0[0] + zz[0 * H_] + bb0[0]);
                    float gf = sigm(a1[0] + zz[1 * H_] + bb0[1]);
                    float gg = tanh_f(a2[0] + zz[2 * H_] + bb0[2]);
                    float go = sigm(a3[0] + zz[3 * H_] + bb0[3]);
                    c0 = gf * c0 + gi * gg;
                    float hh = go * tanh_f(c0);
                    if (l < 16)
                        ((_Float16*)&ring[(t & 63) * 64])[w * 16 + l] = (_Float16)hh;
                    __syncthreads();   // h0(t) visible
                }
            }

            // ---- publish chunk (r13-verified protocol) ----
            {
                if (ch >= GRING) {
                    while (__hip_atomic_load(&done[b], __ATOMIC_ACQUIRE,
                                             __HIP_MEMORY_SCOPE_AGENT) < ch - GRING + 1)
                        __builtin_amdgcn_s_sleep(8);
                    __syncthreads();
                }
                unsigned* dst = h0g + ((size_t)b * GRING + (ch & (GRING - 1))) * H0_DW;
                uint4 v0 = *(const uint4*)&ring[tid * 8];
                uint4 v1 = *(const uint4*)&ring[tid * 8 + 4];
                *(uint4*)&dst[tid * 8]     = v0;
                *(uint4*)&dst[tid * 8 + 4] = v1;
                __syncthreads();   // stores drained (vmcnt) before release
                if (tid == 0)
                    __hip_atomic_store(&prog[b], ch + 1, __ATOMIC_RELEASE,
                                       __HIP_MEMORY_SCOPE_AGENT);
            }
        }
    } else {
        // =================== CONSUMER: layer 1 + OUT (r13 verbatim) ===================
        const int b = blockIdx.x - 64;
        unsigned* h0c    = arena;                    // [64][68] staged h0 (padded)
        unsigned* h1ring = arena + 4352;             // [64][68] h1 ring
        float*    zih1   = (float*)(arena + 8704);   // [32][516] f32
        unsigned* wlin_p = arena + 25216;            // [8][68]

        f16x8 wih1f[4][4], whh1f[4][4];
        #pragma unroll
        for (int j = 0; j < 4; ++j) {
            const int row = j * H_ + w * 16 + n;
            #pragma unroll
            for (int s = 0; s < 4; ++s) {
                const float* p1 = wih1 + (size_t)row * H_ + s * 32 + grp * 8;
                const float* p2 = whh1 + (size_t)row * H_ + s * 32 + grp * 8;
                f16x8 f1, f2;
                #pragma unroll
                for (int jj = 0; jj < 8; ++jj) {
                    f1[jj] = (_Float16)p1[jj];
                    f2[jj] = (_Float16)p2[jj];
                }
                wih1f[j][s] = f1;
                whh1f[j][s] = f2;
            }
        }
        #pragma unroll
        for (int j = 0; j < 4; ++j)
            #pragma unroll
            for (int s = 0; s < 4; ++s) {
                asm("" : "+a"(wih1f[j][s]));
                asm("" : "+a"(whh1f[j][s]));
            }

        float bb1[4];
        #pragma unroll
        for (int j = 0; j < 4; ++j) {
            const int row = j * H_ + w * 16 + n;
            bb1[j] = bih1[row] + bhh1[row];
        }
        {
            float2 v = ((const float2*)wlin)[tid];
            wlin_p[(tid >> 6) * RING_LD + (tid & 63)] = pk2h(v.x, v.y);
        }
        if (tid < F_) blin_f[tid] = blin[tid];
        if (tid < 64) h1ring[63 * RING_LD + tid] = 0u;   // h1(-1) = 0
        __syncthreads();

        float c1 = 0.0f;
        const f32x4 Z4 = {0.0f, 0.0f, 0.0f, 0.0f};

        for (int c = 0; c < NCH; ++c) {
            while (__hip_atomic_load(&prog[b], __ATOMIC_ACQUIRE,
                                     __HIP_MEMORY_SCOPE_AGENT) < c + 1)
                __builtin_amdgcn_s_sleep(8);
            const unsigned* src = h0g + ((size_t)b * GRING + (c & (GRING - 1))) * H0_DW;
            {
                const int tick = tid >> 3;
                const int off  = (tid & 7) * 8;
                uint4 v0 = *(const uint4*)&src[tick * 64 + off];
                uint4 v1 = *(const uint4*)&src[tick * 64 + off + 4];
                *(uint4*)&h0c[tick * RING_LD + off]     = v0;
                *(uint4*)&h0c[tick * RING_LD + off + 4] = v1;
            }
            __syncthreads();   // staged (loads drained)
            if (tid == 0)
                __hip_atomic_store(&done[b], c + 1, __ATOMIC_RELAXED,
                                   __HIP_MEMORY_SCOPE_AGENT);

            for (int half = 0; half < 2; ++half) {
                // ---- batched GEMM: zih1 for 32 ticks ----
                #pragma unroll
                for (int mt = 0; mt < 2; ++mt) {
                    f32x4 d0 = Z4, d1 = Z4, d2 = Z4, d3 = Z4;
                    const int trow = half * 32 + mt * 16 + n;
                    #pragma unroll
                    for (int s = 0; s < 4; ++s) {
                        f16x8 ah = __builtin_bit_cast(
                            f16x8, *(const uint4*)&h0c[trow * RING_LD + s * 16 + grp * 4]);
                        d0 = mfma16(ah, wih1f[0][s], d0);
                        d1 = mfma16(ah, wih1f[1][s], d1);
                        d2 = mfma16(ah, wih1f[2][s], d2);
                        d3 = mfma16(ah, wih1f[3][s], d3);
                    }
                    const int zr = mt * 16 + grp * 4;
                    #pragma unroll
                    for (int reg = 0; reg < 4; ++reg) {
                        zih1[(zr + reg) * Z_LD + 0 * H_ + w * 16 + n] = d0[reg];
                        zih1[(zr + reg) * Z_LD + 1 * H_ + w * 16 + n] = d1[reg];
                        zih1[(zr + reg) * Z_LD + 2 * H_ + w * 16 + n] = d2[reg];
                        zih1[(zr + reg) * Z_LD + 3 * H_ + w * 16 + n] = d3[reg];
                    }
                }
                // no barrier: zih1 cols of wave w written and read only by wave w

                // ---- 32 serial ticks: 4-deep hh1 chain + zih1 scalar ----
                for (int tk = 0; tk < 32; ++tk) {
                    const int t  = c * CHUNK + half * 32 + tk;
                    const unsigned* h1r = &h1ring[((t + 63) & 63) * RING_LD];
                    f32x4 a0, a1, a2, a3;
                    {
                        f16x8 ah = __builtin_bit_cast(f16x8, *(const uint4*)&h1r[grp * 4]);
                        a0 = mfma16(ah, whh1f[0][0], Z4);
                        a1 = mfma16(ah, whh1f[1][0], Z4);
                        a2 = mfma16(ah, whh1f[2][0], Z4);
                        a3 = mfma16(ah, whh1f[3][0], Z4);
                    }
                    #pragma unroll
                    for (int s = 1; s < 4; ++s) {
                        f16x8 ah = __builtin_bit_cast(
                            f16x8, *(const uint4*)&h1r[s * 16 + grp * 4]);
                        a0 = mfma16(ah, whh1f[0][s], a0);
                        a1 = mfma16(ah, whh1f[1][s], a1);
                        a2 = mfma16(ah, whh1f[2][s], a2);
                        a3 = mfma16(ah, whh1f[3][s], a3);
                    }
                    const float* zp = &zih1[tk * Z_LD];
                    float gi = sigm(a0[0] + zp[0 * H_ + w * 16 + n] + bb1[0]);
                    float gf = sigm(a1[0] + zp[1 * H_ + w * 16 + n] + bb1[1]);
                    float gg = tanh_f(a2[0] + zp[2 * H_ + w * 16 + n] + bb1[2]);
                    float go = sigm(a3[0] + zp[3 * H_ + w * 16 + n] + bb1[3]);
                    c1 = gf * c1 + gi * gg;
                    float hh = go * tanh_f(c1);
                    if (l < 16)
                        ((_Float16*)&h1ring[(t & 63) * RING_LD])[w * 16 + l] = (_Float16)hh;
                    __syncthreads();   // h1(t) visible
                }
            }

            // ---- OUT burst for this chunk (r13-verified pattern) ----
            {
                const int tick_i = tid >> 3;
                const int fo     = tid & 7;
                const unsigned* hp = &h1ring[tick_i * RING_LD];
                const unsigned* wv = &wlin_p[fo * RING_LD];
                float a = 0.0f;
                #pragma unroll
                for (int j = 0; j < 16; ++j) {
                    uint4 hv = *(const uint4*)&hp[j * 4];
                    uint4 wq = *(const uint4*)&wv[j * 4];
                    a = fdot2a(wq.x, hv.x, a);
                    a = fdot2a(wq.y, hv.y, a);
                    a = fdot2a(wq.z, hv.z, a);
                    a = fdot2a(wq.w, hv.w, a);
                }
                out[(size_t)b * T_ * F_ + (size_t)c * CHUNK * F_ + tid] = a + blin_f[fo];
                // drains at next chunk's staging barrier
            }
        }
    }
}

// ===================== Fallback (round-5 verified, 3162 us) =====================
__global__ __launch_bounds__(512, 2)
void lstm2_burst_kernel(const float* __restrict__ x,
                        const float* __restrict__ wih0,
                        const float* __restrict__ whh0,
                        const float* __restrict__ bih0,
                        const float* __restrict__ bhh0,
                        const float* __restrict__ wih1,
                        const float* __restrict__ whh1,
                        const float* __restrict__ bih1,
                        const float* __restrict__ bhh1,
                        const float* __restrict__ wlin,
                        const float* __restrict__ blin,
                        float* __restrict__ out)
{
    __shared__ __align__(16) unsigned x_lds[T_ * F_ / 2];
    __shared__ __align__(16) unsigned h0_p[2][H_ / 2];
    __shared__ __align__(16) unsigned h1_ring[64 * RING_LD];
    __shared__ __align__(16) unsigned wlin_p[F_ * RING_LD];
    __shared__ float blin_f[F_];

    const int tid   = threadIdx.x;
    const int b     = blockIdx.x;
    const int h_idx = tid >> 2;
    const int sub   = tid & 3;
    const int grow  = (0x3120 >> (sub * 4)) & 0xF;
    const int row   = grow * H_ + h_idx;

    const float4* xp = (const float4*)(x + (size_t)b * T_ * F_);
    #pragma unroll
    for (int i = 0; i < 8; ++i) {
        int idx = tid + i * 512;
        float4 v = xp[idx];
        x_lds[idx * 2 + 0] = pk2h(v.x, v.y);
        x_lds[idx * 2 + 1] = pk2h(v.z, v.w);
    }

    unsigned rwih0[4];
    {
        const float4* p = (const float4*)(wih0 + (size_t)row * F_);
        float4 v0 = p[0], v1 = p[1];
        rwih0[0] = pk2h(v0.x, v0.y); rwih0[1] = pk2h(v0.z, v0.w);
        rwih0[2] = pk2h(v1.x, v1.y); rwih0[3] = pk2h(v1.z, v1.w);
    }
    unsigned rwhh0[64], rwih1[64], rwhh1[64];
    {
        const float4* p = (const float4*)(whh0 + (size_t)row * H_);
        #pragma unroll
        for (int i = 0; i < 32; ++i) {
            float4 v = p[i];
            rwhh0[i * 2 + 0] = pk2h(v.x, v.y);
            rwhh0[i * 2 + 1] = pk2h(v.z, v.w);
        }
    }
    {
        const float4* p = (const float4*)(wih1 + (size_t)row * H_);
        #pragma unroll
        for (int i = 0; i < 32; ++i) {
            float4 v = p[i];
            rwih1[i * 2 + 0] = pk2h(v.x, v.y);
            rwih1[i * 2 + 1] = pk2h(v.z, v.w);
        }
    }
    {
        const float4* p = (const float4*)(whh1 + (size_t)row * H_);
        #pragma unroll
        for (int i = 0; i < 32; ++i) {
            float4 v = p[i];
            rwhh1[i * 2 + 0] = pk2h(v.x, v.y);
            rwhh1[i * 2 + 1] = pk2h(v.z, v.w);
        }
    }
    const float bias0 = bih0[row] + bhh0[row];
    const float bias1 = bih1[row] + bhh1[row];

    {
        int r = tid >> 6, c = tid & 63;
        float2 v = ((const float2*)wlin)[r * 64 + c];
        wlin_p[r * RING_LD + c] = pk2h(v.x, v.y);
    }
    if (tid < F_) blin_f[tid] = blin[tid];
    if (tid < H_ / 2) { h0_p[0][tid] = 0u; h0_p[1][tid] = 0u; }
    if (tid < H_ / 2) h1_ring[63 * RING_LD + tid] = 0u;
    __syncthreads();

    const bool is_g = (sub == 1);
    const bool lo2  = (sub < 2);
    float c0 = 0.0f, c1 = 0.0f;

    for (int t = 0; t < T_; ++t) {
        const int rp = (t + 1) & 1;
        const int wp = t & 1;
        {
            float aa = bias0, ab = 0.0f;
            uint4 xv = *(const uint4*)&x_lds[t * 4];
            aa = fdot2a(rwih0[0], xv.x, aa);
            ab = fdot2a(rwih0[1], xv.y, ab);
            aa = fdot2a(rwih0[2], xv.z, aa);
            ab = fdot2a(rwih0[3], xv.w, ab);
            const unsigned* hr = &h0_p[rp][0];
            #pragma unroll
            for (int j = 0; j < 16; ++j) {
                uint4 hv = *(const uint4*)&hr[j * 4];
                aa = fdot2a(rwhh0[j * 4 + 0], hv.x, aa);
                ab = fdot2a(rwhh0[j * 4 + 1], hv.y, ab);
                aa = fdot2a(rwhh0[j * 4 + 2], hv.z, aa);
                ab = fdot2a(rwhh0[j * 4 + 3], hv.w, ab);
            }
            float a = aa + ab;
            float xin = is_g ? 2.0f * a : a;
            float s   = sigm(xin);
            float act = is_g ? 2.0f * s - 1.0f : s;
            float s1  = lane_xor1(act);
            float p   = lo2 ? act * s1 : (sub == 2 ? act : s1) * c0;
            float cn  = p + lane_xor2(p);
            c0 = cn;
            float oval = (sub == 2) ? s1 : act;
            float h = oval * tanh_f(cn);
            if (sub == 2) ((_Float16*)&h0_p[wp][0])[h_idx] = (_Float16)h;
        }
        __syncthreads();
        {
            float aa = bias1, ab = 0.0f, ba = 0.0f, bb = 0.0f;
            const unsigned* h0r = &h0_p[wp][0];
            const unsigned* h1r = &h1_ring[((t + 63) & 63) * RING_LD];
            #pragma unroll
            for (int j = 0; j < 16; ++j) {
                uint4 hv0 = *(const uint4*)&h0r[j * 4];
                uint4 hv1 = *(const uint4*)&h1r[j * 4];
                aa = fdot2a(rwih1[j * 4 + 0], hv0.x, aa);
                ab = fdot2a(rwih1[j * 4 + 1], hv0.y, ab);
                aa = fdot2a(rwih1[j * 4 + 2], hv0.z, aa);
                ab = fdot2a(rwih1[j * 4 + 3], hv0.w, ab);
                ba = fdot2a(rwhh1[j * 4 + 0], hv1.x, ba);
                bb = fdot2a(rwhh1[j * 4 + 1], hv1.y, bb);
                ba = fdot2a(rwhh1[j * 4 + 2], hv1.z, ba);
                bb = fdot2a(rwhh1[j * 4 + 3], hv1.w, bb);
            }
            float a = (aa + ab) + (ba + bb);
            float xin = is_g ? 2.0f * a : a;
            float s   = sigm(xin);
            float act = is_g ? 2.0f * s - 1.0f : s;
            float s1  = lane_xor1(act);
            float p   = lo2 ? act * s1 : (sub == 2 ? act : s1) * c1;
            float cn  = p + lane_xor2(p);
            c1 = cn;
            float oval = (sub == 2) ? s1 : act;
            float h = oval * tanh_f(cn);
            if (sub == 2)
                ((_Float16*)&h1_ring[(t & 63) * RING_LD])[h_idx] = (_Float16)h;
        }
        __syncthreads();
        if ((t & 63) == 63) {
            const int tick_i = tid >> 3;
            const int fo     = tid & 7;
            const unsigned* hp = &h1_ring[tick_i * RING_LD];
            const unsigned* wv = &wlin_p[fo * RING_LD];
            float a = 0.0f;
            #pragma unroll
            for (int j = 0; j < 16; ++j) {
                uint4 hv = *(const uint4*)&hp[j * 4];
                uint4 wq = *(const uint4*)&wv[j * 4];
                a = fdot2a(wq.x, hv.x, a);
                a = fdot2a(wq.y, hv.y, a);
                a = fdot2a(wq.z, hv.z, a);
                a = fdot2a(wq.w, hv.w, a);
            }
            out[(size_t)b * T_ * F_ + (size_t)(t - 63) * F_ + tid] = a + blin_f[fo];
        }
    }
}

extern "C" void kernel_launch(void* const* d_in, const int* in_sizes, int n_in,
                              void* d_out, int out_size, void* d_ws, size_t ws_size,
                              hipStream_t stream) {
    const float* x    = (const float*)d_in[0];
    const float* wih0 = (const float*)d_in[1];
    const float* whh0 = (const float*)d_in[2];
    const float* bih0 = (const float*)d_in[3];
    const float* bhh0 = (const float*)d_in[4];
    const float* wih1 = (const float*)d_in[5];
    const float* whh1 = (const float*)d_in[6];
    const float* bih1 = (const float*)d_in[7];
    const float* bhh1 = (const float*)d_in[8];
    const float* wlin = (const float*)d_in[9];
    const float* blin = (const float*)d_in[10];
    float* out = (float*)d_out;

    const size_t h0_bytes = (size_t)B_ * GRING * H0_DW * sizeof(unsigned);  // 16 MB
    const size_t need = h0_bytes + 512;
    if (d_ws != nullptr && ws_size >= need) {
        unsigned* h0g = (unsigned*)d_ws;
        int* flags = (int*)((char*)d_ws + h0_bytes);   // prog[64], done[64]
        hipMemsetAsync(flags, 0, 512, stream);
        lstm2_pc5_kernel<<<dim3(128), dim3(512), 0, stream>>>(
            x, wih0, whh0, bih0, bhh0, wih1, whh1, bih1, bhh1, wlin, blin,
            h0g, flags, out);
    } else {
        lstm2_burst_kernel<<<dim3(B_), dim3(512), 0, stream>>>(
            x, wih0, whh0, bih0, bhh0, wih1, whh1, bih1, bhh1, wlin, blin, out);
    }
}